// Round 2
// baseline (681.114 us; speedup 1.0000x reference)
//
#include <hip/hip_runtime.h>

#define TDIM 512             // T, fixed by the problem
#define ROWS_PER_WAVE 32
#define WAVES_PER_BLOCK 4
#define ROWS_PER_BLOCK (ROWS_PER_WAVE * WAVES_PER_BLOCK)  // 128
#define NSLOTS 64            // partial-sum slots (one wave reads them back)

__global__ __launch_bounds__(256) void surv_loss_kernel(
    const float* __restrict__ y_pred,
    const int* __restrict__ y,
    const int* __restrict__ status,
    float* __restrict__ out,
    unsigned char* __restrict__ ws,
    int nrows, int nblocks) {
  double* acc = reinterpret_cast<double*>(ws);                       // NSLOTS doubles
  unsigned int* counter = reinterpret_cast<unsigned int*>(ws + NSLOTS * 8);

  const int lane = threadIdx.x & 63;
  const int widb = threadIdx.x >> 6;                  // wave in block (0..3)
  const int gwave = blockIdx.x * WAVES_PER_BLOCK + widb;
  const long r0 = (long)gwave * ROWS_PER_WAVE;        // contiguous 32-row chunk

  float lacc = 0.0f;                                  // per-lane accumulator

  // ---- load this wave's 32 (y, status) pairs: lanes 0..31 (dup on 32..63)
  const int lrow = (int)r0 + (lane & 31);
  const bool lvalid = lrow < nrows;
  const int lclamp = lvalid ? lrow : (nrows - 1);
  const int v_l = y[lclamp];
  const int st_l = status[lclamp];

  // ---- status==1 rows: ONE gather across lanes 0..31, one logf
  {
    const bool g = (lane < 32) && lvalid && (st_l == 1);
    float pv = 1.0f;
    if (g) pv = y_pred[(size_t)lclamp * TDIM + v_l];
    if (g) lacc -= logf(pv);
  }

  // ---- status==0 rows: 8 lanes per row, 8 rows per batch, 4 batches
  const int g8 = lane >> 3;   // row-group within batch (0..7)
  const int t8 = lane & 7;    // lane within group
  #pragma unroll
  for (int b = 0; b < 4; ++b) {
    const int k = b * 8 + g8;                         // row idx in wave chunk
    const int vk = __shfl(v_l, k, 64);
    const int stk = __shfl(st_l, k, 64);
    const long row = r0 + k;
    const bool rvalid = (row < (long)nrows) && (stk == 0);
    const int ve = rvalid ? vk : 0;                   // 0 => all loads masked off
    const float* rowp = y_pred + (size_t)row * TDIM;

    float s = 0.0f;
    #pragma unroll
    for (int p = 0; p < 16; ++p) {                    // 16 × 32 elems = 512
      const int e = p * 32 + t8 * 4;
      if (e < ve) {
        float4 d = *reinterpret_cast<const float4*>(rowp + e);
        s += d.x;
        if (e + 1 < ve) s += d.y;
        if (e + 2 < ve) s += d.z;
        if (e + 3 < ve) s += d.w;
      }
    }
    // reduce across the 8-lane group (3 stages)
    s += __shfl_xor(s, 1, 64);
    s += __shfl_xor(s, 2, 64);
    s += __shfl_xor(s, 4, 64);
    if (rvalid && t8 == 0) lacc -= logf(1.0f - s);
  }

  // ---- wave reduce + block reduce
  #pragma unroll
  for (int off = 32; off >= 1; off >>= 1) lacc += __shfl_xor(lacc, off, 64);

  __shared__ float sm[WAVES_PER_BLOCK];
  __shared__ int is_last;
  if (lane == 0) sm[widb] = lacc;
  __syncthreads();
  if (threadIdx.x == 0) {
    const float bsum = sm[0] + sm[1] + sm[2] + sm[3];
    atomicAdd(&acc[blockIdx.x & (NSLOTS - 1)], (double)bsum);
    __threadfence();
    const unsigned int old = atomicAdd(counter, 1u);
    is_last = (old == (unsigned int)(nblocks - 1)) ? 1 : 0;
  }
  __syncthreads();

  // ---- last block: 64 parallel coherent slot reads + wave reduce
  if (is_last && threadIdx.x < NSLOTS) {
    double myv = atomicAdd(&acc[threadIdx.x], 0.0);   // coherent read of final slot
    #pragma unroll
    for (int off = 32; off >= 1; off >>= 1) myv += __shfl_xor(myv, off, 64);
    if (threadIdx.x == 0) out[0] = (float)myv;
  }
}

extern "C" void kernel_launch(void* const* d_in, const int* in_sizes, int n_in,
                              void* d_out, int out_size, void* d_ws, size_t ws_size,
                              hipStream_t stream) {
  const float* y_pred = (const float*)d_in[0];
  const int* y = (const int*)d_in[1];
  const int* status = (const int*)d_in[2];
  float* out = (float*)d_out;
  const int nrows = in_sizes[1];  // B = 262144

  // zero accumulator slots + finish counter (ws re-poisoned 0xAA each call)
  hipMemsetAsync(d_ws, 0, NSLOTS * 8 + 8, stream);

  const int nblocks = (nrows + ROWS_PER_BLOCK - 1) / ROWS_PER_BLOCK;  // 2048
  surv_loss_kernel<<<nblocks, 256, 0, stream>>>(y_pred, y, status, out,
                                                (unsigned char*)d_ws, nrows, nblocks);
}